// Round 4
// baseline (313.578 us; speedup 1.0000x reference)
//
#include <hip/hip_runtime.h>
#include <cstdint>
#include <cstddef>

#define DEVI __device__ __forceinline__

typedef short    shortx8 __attribute__((ext_vector_type(8)));
typedef short    shortx4 __attribute__((ext_vector_type(4)));
typedef short    shortx2 __attribute__((ext_vector_type(2)));
typedef __bf16   bf16x8  __attribute__((ext_vector_type(8)));
typedef float    floatx4 __attribute__((ext_vector_type(4)));

DEVI unsigned short f2b(float f) {
    union { float f; unsigned u; } a; a.f = f;
    unsigned r = a.u + 0x7fffu + ((a.u >> 16) & 1u);
    return (unsigned short)(r >> 16);
}
DEVI float b2f(unsigned short u) {
    union { unsigned u; float f; } a; a.u = ((unsigned)u) << 16;
    return a.f;
}

DEVI floatx4 mfma_bf16(bf16x8 a, bf16x8 b, floatx4 c) {
    return __builtin_amdgcn_mfma_f32_16x16x32_bf16(a, b, c, 0, 0, 0);
}

DEVI void glds16(const ushort* g, ushort* l) {
    __builtin_amdgcn_global_load_lds(
        (const __attribute__((address_space(1))) void*)g,
        (__attribute__((address_space(3))) void*)l, 16, 0, 0);
}

// ---------------- fused prep: x->bf16, W transposes, bias pack ----------------
__global__ void k_prep(const float* __restrict__ x, ushort* __restrict__ xb,
                       const float* __restrict__ Wq, const float* __restrict__ Wk,
                       const float* __restrict__ Wv, const float* __restrict__ Wo,
                       ushort* __restrict__ Wt, ushort* __restrict__ Wot,
                       const float* __restrict__ bq, const float* __restrict__ bk,
                       const float* __restrict__ bv, float* __restrict__ bqkv) {
    __shared__ float tile[64][65];
    const int bid = blockIdx.x, t = threadIdx.x;
    if (bid < 6144) {                      // x -> bf16
        size_t i = ((size_t)bid * 256 + t) * 8;
        float4 v0 = *(const float4*)(x + i);
        float4 v1 = *(const float4*)(x + i + 4);
        shortx8 o;
        o[0] = (short)f2b(v0.x); o[1] = (short)f2b(v0.y);
        o[2] = (short)f2b(v0.z); o[3] = (short)f2b(v0.w);
        o[4] = (short)f2b(v1.x); o[5] = (short)f2b(v1.y);
        o[6] = (short)f2b(v1.z); o[7] = (short)f2b(v1.w);
        *(shortx8*)(xb + i) = o;
    } else if (bid < 6720) {               // W [in][out] fp32 -> [out][in] bf16
        int pid = bid - 6144;
        int zi = pid / 144, rem = pid % 144;
        const float* W = (zi == 0) ? Wq : (zi == 1) ? Wk : (zi == 2) ? Wv : Wo;
        const int i0 = (rem / 12) * 64, j0 = (rem % 12) * 64;
        const int c = t & 63, r4 = t >> 6;
        for (int rr = r4; rr < 64; rr += 4)
            tile[rr][c] = W[(size_t)(i0 + rr) * 768 + j0 + c];
        __syncthreads();
        ushort* dst = (zi < 3) ? (Wt + (size_t)(zi * 768) * 768) : Wot;
        for (int jj = r4; jj < 64; jj += 4)
            dst[(size_t)(j0 + jj) * 768 + i0 + c] = f2b(tile[c][jj]);
    } else {                               // bias pack
        int j = (bid - 6720) * 256 + t;
        if (j < 2304) {
            const float* src = (j < 768) ? bq : (j < 1536) ? bk : bv;
            bqkv[j] = src[j % 768];
        }
    }
}

// ---------------- main GEMM: half-flatmm ----------------
// A staged to LDS via global_load_lds (XOR chunk swizzle, BK=64); B-fragments
// loaded DIRECTLY from global (L2-resident weights) into registers — no LDS
// round-trip for B. Per instr the B gather is 16 rows x 64B contiguous.
template <int MODE>
__global__ __launch_bounds__(256, 3) void k_gemm(
    const ushort* __restrict__ A, const ushort* __restrict__ Bt,
    const float* __restrict__ bias, void* __restrict__ Cout, int Ncols) {
    constexpr int K = 768;
    __shared__ ushort As[128 * 64];
    const int m0 = blockIdx.x * 128;
    const int n0 = blockIdx.y * 128;
    const int tid = threadIdx.x;
    const int w = tid >> 6, lane = tid & 63;

    const int lr = lane >> 3;                    // staging row within 8-row slab
    const int lc = ((lane & 7) ^ lr) * 8;        // swizzled source chunk
    const ushort* ag[4]; ushort* al[4];
#pragma unroll
    for (int i = 0; i < 4; ++i) {
        ag[i] = A + (size_t)(m0 + w * 32 + i * 8 + lr) * K + lc;
        al[i] = As + (w * 32 + i * 8) * 64;      // wave-uniform LDS bases
    }

    const int rBase = (w >> 1) * 64;
    const int nBase = (w & 1) * 64;
    const int fr = lane & 15;
    const int q4 = lane >> 4;

    const ushort* bp[4];
#pragma unroll
    for (int nt = 0; nt < 4; ++nt)
        bp[nt] = Bt + (size_t)(n0 + nBase + nt * 16 + fr) * K + q4 * 8;

    floatx4 acc[4][4] = {};

    for (int k0 = 0; k0 < K; k0 += 64) {
#pragma unroll
        for (int i = 0; i < 4; ++i) glds16(ag[i] + k0, al[i]);
        bf16x8 bf[2][4];
#pragma unroll
        for (int kc = 0; kc < 2; ++kc)
#pragma unroll
            for (int nt = 0; nt < 4; ++nt)
                bf[kc][nt] = *(const bf16x8*)(bp[nt] + k0 + kc * 32);
        __syncthreads();   // drains vmcnt(0): A staged, B in regs
#pragma unroll
        for (int kc = 0; kc < 2; ++kc) {
            const int off = ((kc * 4 + q4) ^ (fr & 7)) * 8;
            bf16x8 af[4];
#pragma unroll
            for (int rt = 0; rt < 4; ++rt)
                af[rt] = *(const bf16x8*)(As + (rBase + rt * 16 + fr) * 64 + off);
#pragma unroll
            for (int rt = 0; rt < 4; ++rt)
#pragma unroll
                for (int nt = 0; nt < 4; ++nt)
                    acc[rt][nt] = mfma_bf16(af[rt], bf[kc][nt], acc[rt][nt]);
        }
        __syncthreads();   // protect As against next iteration's staging
    }

#pragma unroll
    for (int rt = 0; rt < 4; ++rt) {
#pragma unroll
        for (int nt = 0; nt < 4; ++nt) {
#pragma unroll
            for (int r = 0; r < 4; ++r) {
                int m = m0 + rBase + rt * 16 + q4 * 4 + r;
                int n = n0 + nBase + nt * 16 + fr;
                float v = acc[rt][nt][r] + bias[n];
                if (MODE == 0) {
                    if (n < 1536) v = (v > 0.f) ? (v + 1.f) : __expf(v);  // phi
                    ((ushort*)Cout)[(size_t)m * Ncols + n] = f2b(v);
                } else {
                    ((float*)Cout)[(size_t)m * Ncols + n] = v;
                }
            }
        }
    }
}

// ---------------- kv + ksum via MFMA (stride 70: conflict-free reads) ---------
__global__ __launch_bounds__(256) void k_kv(const ushort* __restrict__ QKV,
                                            float* __restrict__ kvp) {
    const int bh = blockIdx.x, s = blockIdx.y;
    const int bb = bh / 12, head = bh % 12;
    __shared__ ushort kS[64 * 70];
    __shared__ ushort vS[64 * 70];
    const int t = threadIdx.x, w = t >> 6, lane = t & 63;
    const int fr = lane & 15, fk = (lane >> 4) * 8;

    floatx4 acc[5] = {};
    const int n_ld = t >> 2, c16 = (t & 3) * 16;
    const ushort* base = QKV + (size_t)(bb * 4096 + s * 512) * 2304 + 768 + head * 64 + c16;

    for (int rr = 0; rr < 8; ++rr) {
        if (rr) __syncthreads();
        {
            const ushort* kp = base + (size_t)(rr * 64 + n_ld) * 2304;
            union { shortx8 v8; shortx2 v2[4]; } k0, k1, v0, v1;
            k0.v8 = *(const shortx8*)(kp);
            k1.v8 = *(const shortx8*)(kp + 8);
            v0.v8 = *(const shortx8*)(kp + 768);
            v1.v8 = *(const shortx8*)(kp + 776);
            ushort* kd = kS + n_ld * 70 + c16;
            ushort* vd = vS + n_ld * 70 + c16;
#pragma unroll
            for (int i = 0; i < 4; ++i) {
                *(shortx2*)(kd + 2 * i)     = k0.v2[i];
                *(shortx2*)(kd + 8 + 2 * i) = k1.v2[i];
                *(shortx2*)(vd + 2 * i)     = v0.v2[i];
                *(shortx2*)(vd + 8 + 2 * i) = v1.v2[i];
            }
        }
        __syncthreads();
#pragma unroll
        for (int kl = 0; kl < 64; kl += 32) {
            union { bf16x8 v; ushort u[8]; } bfr, afr[4];
#pragma unroll
            for (int i = 0; i < 8; ++i) {
                int n = kl + fk + i;
                bfr.u[i] = kS[n * 70 + w * 16 + fr];
#pragma unroll
                for (int mt = 0; mt < 4; ++mt)
                    afr[mt].u[i] = vS[n * 70 + mt * 16 + fr];
            }
            union { bf16x8 v; ushort u[8]; } ones;
            ushort ov = (fr == 0) ? (ushort)0x3F80 : (ushort)0;
#pragma unroll
            for (int i = 0; i < 8; ++i) ones.u[i] = ov;
#pragma unroll
            for (int mt = 0; mt < 4; ++mt)
                acc[mt] = mfma_bf16(afr[mt].v, bfr.v, acc[mt]);
            acc[4] = mfma_bf16(ones.v, bfr.v, acc[4]);
        }
    }

    float* dst = kvp + ((size_t)bh * 8 + s) * (65 * 64);
#pragma unroll
    for (int mt = 0; mt < 4; ++mt)
#pragma unroll
        for (int r = 0; r < 4; ++r)
            dst[(mt * 16 + (lane >> 4) * 4 + r) * 64 + w * 16 + fr] = acc[mt][r];
    if (lane < 16) dst[64 * 64 + w * 16 + lane] = acc[4][0];
}

// reduce 8 partials, emit bf16: kvb [48][65][64]
__global__ void k_kvred(const float* __restrict__ kvp, ushort* __restrict__ kvb) {
    int t4 = (blockIdx.x * 256 + threadIdx.x) * 4;   // 195*256*4 == 199680
    int bh = t4 / 4160, rem = t4 % 4160;
    const float* p = kvp + (size_t)bh * 8 * 4160 + rem;
    float4 sum = {0.f, 0.f, 0.f, 0.f};
    for (int i = 0; i < 8; ++i) {
        float4 a = *(const float4*)(p + (size_t)i * 4160);
        sum.x += a.x; sum.y += a.y; sum.z += a.z; sum.w += a.w;
    }
    shortx4 o;
    o[0] = (short)f2b(sum.x); o[1] = (short)f2b(sum.y);
    o[2] = (short)f2b(sum.z); o[3] = (short)f2b(sum.w);
    *(shortx4*)(kvb + t4) = o;
}

// ---------------- num + z + normed (MFMA) ----------------
__global__ __launch_bounds__(256) void k_num(const ushort* __restrict__ QKV,
                                             const ushort* __restrict__ kvb,
                                             ushort* __restrict__ normed) {
    const int bh = blockIdx.x, l0 = blockIdx.y * 128;
    const int bb = bh / 12, head = bh % 12;
    __shared__ ushort qsh[128 * 72];
    __shared__ ushort kvT[80 * 72];
    __shared__ float dnm[128];
    const int t = threadIdx.x, w = t >> 6, lane = t & 63;

    {
        const ushort* kvbb = kvb + (size_t)bh * 4160;
        int c8 = (t & 7) * 8;
        for (int r0 = (t >> 3); r0 < 65; r0 += 32)
            *(shortx8*)(kvT + r0 * 72 + c8) = *(const shortx8*)(kvbb + r0 * 64 + c8);
    }
    for (int idx = t; idx < 15 * 72; idx += 256) kvT[65 * 72 + idx] = 0;

    const ushort* qg = QKV + (size_t)(bb * 4096 + l0) * 2304 + head * 64;
    {
        int row = t >> 3, c8 = (t & 7) * 8;
#pragma unroll
        for (int i = 0; i < 4; ++i) {
            shortx8 v = *(const shortx8*)(qg + (size_t)(i * 32 + row) * 2304 + c8);
            *(shortx8*)(qsh + (i * 32 + row) * 72 + c8) = v;
        }
    }
    __syncthreads();

    const int fr = lane & 15, fk = (lane >> 4) * 8;
    floatx4 acc[2][5] = {};
#pragma unroll
    for (int kc = 0; kc < 2; ++kc) {
        bf16x8 a[2], b[5];
#pragma unroll
        for (int rt = 0; rt < 2; ++rt)
            a[rt] = *(const bf16x8*)(qsh + (w * 32 + rt * 16 + fr) * 72 + kc * 32 + fk);
#pragma unroll
        for (int nt = 0; nt < 5; ++nt)
            b[nt] = *(const bf16x8*)(kvT + (nt * 16 + fr) * 72 + kc * 32 + fk);
#pragma unroll
        for (int rt = 0; rt < 2; ++rt)
#pragma unroll
            for (int nt = 0; nt < 5; ++nt)
                acc[rt][nt] = mfma_bf16(a[rt], b[nt], acc[rt][nt]);
    }
    if (fr == 0) {
#pragma unroll
        for (int rt = 0; rt < 2; ++rt)
#pragma unroll
            for (int r = 0; r < 4; ++r)
                dnm[w * 32 + rt * 16 + (lane >> 4) * 4 + r] = acc[rt][4][r];
    }
    __syncthreads();

    // scale + stage to LDS (reuse qsh, stride 72), then vector-store
    ushort* osh = qsh;
#pragma unroll
    for (int rt = 0; rt < 2; ++rt) {
#pragma unroll
        for (int r = 0; r < 4; ++r) {
            int ml = w * 32 + rt * 16 + (lane >> 4) * 4 + r;
            float z = 1.f / dnm[ml];
#pragma unroll
            for (int nt = 0; nt < 4; ++nt)
                osh[ml * 72 + nt * 16 + fr] = f2b(acc[rt][nt][r] * z);
        }
    }
    __syncthreads();
    {
        int row = t >> 3, c8 = (t & 7) * 8;
#pragma unroll
        for (int i = 0; i < 4; ++i) {
            int r2 = i * 32 + row;
            *(shortx8*)(normed + (size_t)(bb * 4096 + l0 + r2) * 768 + head * 64 + c8) =
                *(const shortx8*)(osh + r2 * 72 + c8);
        }
    }
}

// ---------------- launch ----------------
extern "C" void kernel_launch(void* const* d_in, const int* in_sizes, int n_in,
                              void* d_out, int out_size, void* d_ws, size_t ws_size,
                              hipStream_t stream) {
    const float* x  = (const float*)d_in[0];
    const float* Wq = (const float*)d_in[1];
    const float* bq = (const float*)d_in[2];
    const float* Wk = (const float*)d_in[3];
    const float* bk = (const float*)d_in[4];
    const float* Wv = (const float*)d_in[5];
    const float* bv = (const float*)d_in[6];
    const float* Wo = (const float*)d_in[7];
    const float* bo = (const float*)d_in[8];

    char* ws = (char*)d_ws;
    ushort* Xb   = (ushort*)(ws);                 // 25,165,824 B (reused as normed)
    ushort* Wt   = (ushort*)(ws + 25165824);      //  3,538,944 B
    ushort* Wot  = (ushort*)(ws + 28704768);      //  1,179,648 B
    float*  bqkv = (float*)(ws + 29884416);       //      9,216 B
    ushort* QKV  = (ushort*)(ws + 29893632);      // 75,497,472 B
    float*  kvp  = (float*)(ws + 105391104);      //  6,389,760 B
    ushort* kvb  = (ushort*)(ws + 111780864);     //    399,360 B
    ushort* normed = Xb;

    k_prep <<<dim3(6729),      256, 0, stream>>>(x, Xb, Wq, Wk, Wv, Wo, Wt, Wot,
                                                 bq, bk, bv, bqkv);
    k_gemm<0><<<dim3(128, 18), 256, 0, stream>>>(Xb, Wt, bqkv, (void*)QKV, 2304);
    k_kv   <<<dim3(48, 8),     256, 0, stream>>>(QKV, kvp);
    k_kvred<<<dim3(195),       256, 0, stream>>>(kvp, kvb);
    k_num  <<<dim3(48, 32),    256, 0, stream>>>(QKV, kvb, normed);
    k_gemm<1><<<dim3(128, 6),  256, 0, stream>>>(normed, Wot, bo, d_out, 768);
}

// Round 5
// 245.709 us; speedup vs baseline: 1.2762x; 1.2762x over previous
//
#include <hip/hip_runtime.h>
#include <cstdint>
#include <cstddef>

#define DEVI __device__ __forceinline__

typedef short    shortx8 __attribute__((ext_vector_type(8)));
typedef short    shortx4 __attribute__((ext_vector_type(4)));
typedef short    shortx2 __attribute__((ext_vector_type(2)));
typedef __bf16   bf16x8  __attribute__((ext_vector_type(8)));
typedef float    floatx4 __attribute__((ext_vector_type(4)));

DEVI unsigned short f2b(float f) {
    union { float f; unsigned u; } a; a.f = f;
    unsigned r = a.u + 0x7fffu + ((a.u >> 16) & 1u);
    return (unsigned short)(r >> 16);
}
DEVI float b2f(unsigned short u) {
    union { unsigned u; float f; } a; a.u = ((unsigned)u) << 16;
    return a.f;
}

DEVI floatx4 mfma_bf16(bf16x8 a, bf16x8 b, floatx4 c) {
    return __builtin_amdgcn_mfma_f32_16x16x32_bf16(a, b, c, 0, 0, 0);
}

DEVI void glds16(const ushort* g, ushort* l) {
    __builtin_amdgcn_global_load_lds(
        (const __attribute__((address_space(1))) void*)g,
        (__attribute__((address_space(3))) void*)l, 16, 0, 0);
}

// ---------------- fused prep: x->bf16, W transposes, bias pack ----------------
__global__ void k_prep(const float* __restrict__ x, ushort* __restrict__ xb,
                       const float* __restrict__ Wq, const float* __restrict__ Wk,
                       const float* __restrict__ Wv, const float* __restrict__ Wo,
                       ushort* __restrict__ Wt, ushort* __restrict__ Wot,
                       const float* __restrict__ bq, const float* __restrict__ bk,
                       const float* __restrict__ bv, float* __restrict__ bqkv) {
    __shared__ float tile[64][65];
    const int bid = blockIdx.x, t = threadIdx.x;
    if (bid < 6144) {                      // x -> bf16
        size_t i = ((size_t)bid * 256 + t) * 8;
        float4 v0 = *(const float4*)(x + i);
        float4 v1 = *(const float4*)(x + i + 4);
        shortx8 o;
        o[0] = (short)f2b(v0.x); o[1] = (short)f2b(v0.y);
        o[2] = (short)f2b(v0.z); o[3] = (short)f2b(v0.w);
        o[4] = (short)f2b(v1.x); o[5] = (short)f2b(v1.y);
        o[6] = (short)f2b(v1.z); o[7] = (short)f2b(v1.w);
        *(shortx8*)(xb + i) = o;
    } else if (bid < 6720) {               // W [in][out] fp32 -> [out][in] bf16
        int pid = bid - 6144;
        int zi = pid / 144, rem = pid % 144;
        const float* W = (zi == 0) ? Wq : (zi == 1) ? Wk : (zi == 2) ? Wv : Wo;
        const int i0 = (rem / 12) * 64, j0 = (rem % 12) * 64;
        const int c = t & 63, r4 = t >> 6;
        for (int rr = r4; rr < 64; rr += 4)
            tile[rr][c] = W[(size_t)(i0 + rr) * 768 + j0 + c];
        __syncthreads();
        ushort* dst = (zi < 3) ? (Wt + (size_t)(zi * 768) * 768) : Wot;
        for (int jj = r4; jj < 64; jj += 4)
            dst[(size_t)(j0 + jj) * 768 + i0 + c] = f2b(tile[c][jj]);
    } else {                               // bias pack
        int j = (bid - 6720) * 256 + t;
        if (j < 2304) {
            const float* src = (j < 768) ? bq : (j < 1536) ? bk : bv;
            bqkv[j] = src[j % 768];
        }
    }
}

// ---------------- main GEMM: 256x128 block, 128x64 wave tile, BK=64 ----------
// Both operands staged to LDS via global_load_lds with the XOR chunk swizzle
// (element (r,k) at r*64 + ((k>>3)^(r&7))*8 + (k&7)); fragment reads XOR back.
// 128x64 wave tile: 42.7 FLOP per LDS byte (vs 21.8 at 64x64) -> LDS-pipe
// ceiling lifts from ~47% to ~62% MfmaUtil.
template <int MODE>
__global__ __launch_bounds__(256, 2) void k_gemm(
    const ushort* __restrict__ A, const ushort* __restrict__ Bt,
    const float* __restrict__ bias, void* __restrict__ Cout, int Ncols) {
    constexpr int K = 768;
    __shared__ ushort As[256 * 64];
    __shared__ ushort Bs[128 * 64];
    const int m0 = blockIdx.x * 256;
    const int n0 = blockIdx.y * 128;
    const int tid = threadIdx.x;
    const int w = tid >> 6, lane = tid & 63;

    const int lr = lane >> 3;                    // staging row within 8-row slab
    const int lc = ((lane & 7) ^ lr) * 8;        // swizzled source chunk
    const ushort* ag[8]; ushort* al[8];
    const ushort* bg[4]; ushort* bl[4];
#pragma unroll
    for (int i = 0; i < 8; ++i) {                // wave w stages A rows w*64..+64
        ag[i] = A + (size_t)(m0 + w * 64 + i * 8 + lr) * K + lc;
        al[i] = As + (w * 64 + i * 8) * 64;
    }
#pragma unroll
    for (int i = 0; i < 4; ++i) {                // and B rows w*32..+32
        bg[i] = Bt + (size_t)(n0 + w * 32 + i * 8 + lr) * K + lc;
        bl[i] = Bs + (w * 32 + i * 8) * 64;
    }

    const int rBase = (w >> 1) * 128;            // wave tile: 128 m x 64 n
    const int nBase = (w & 1) * 64;
    const int fr = lane & 15;
    const int q4 = lane >> 4;

    floatx4 acc[8][4] = {};

    for (int k0 = 0; k0 < K; k0 += 64) {
#pragma unroll
        for (int i = 0; i < 8; ++i) glds16(ag[i] + k0, al[i]);
#pragma unroll
        for (int i = 0; i < 4; ++i) glds16(bg[i] + k0, bl[i]);
        __syncthreads();
#pragma unroll
        for (int kc = 0; kc < 2; ++kc) {
            const int off = ((kc * 4 + q4) ^ (fr & 7)) * 8;
            bf16x8 bf[4];
#pragma unroll
            for (int nt = 0; nt < 4; ++nt)
                bf[nt] = *(const bf16x8*)(Bs + (nBase + nt * 16 + fr) * 64 + off);
#pragma unroll
            for (int rt = 0; rt < 8; ++rt) {     // stream A-frags against held B
                bf16x8 af = *(const bf16x8*)(As + (rBase + rt * 16 + fr) * 64 + off);
#pragma unroll
                for (int nt = 0; nt < 4; ++nt)
                    acc[rt][nt] = mfma_bf16(af, bf[nt], acc[rt][nt]);
            }
        }
        __syncthreads();
    }

#pragma unroll
    for (int rt = 0; rt < 8; ++rt) {
#pragma unroll
        for (int nt = 0; nt < 4; ++nt) {
#pragma unroll
            for (int r = 0; r < 4; ++r) {
                int m = m0 + rBase + rt * 16 + q4 * 4 + r;
                int n = n0 + nBase + nt * 16 + fr;
                float v = acc[rt][nt][r] + bias[n];
                if (MODE == 0) {
                    if (n < 1536) v = (v > 0.f) ? (v + 1.f) : __expf(v);  // phi
                    ((ushort*)Cout)[(size_t)m * Ncols + n] = f2b(v);
                } else {
                    ((float*)Cout)[(size_t)m * Ncols + n] = v;
                }
            }
        }
    }
}

// ---------------- kv + ksum via MFMA (stride 70: conflict-free reads) ---------
__global__ __launch_bounds__(256) void k_kv(const ushort* __restrict__ QKV,
                                            float* __restrict__ kvp) {
    const int bh = blockIdx.x, s = blockIdx.y;
    const int bb = bh / 12, head = bh % 12;
    __shared__ ushort kS[64 * 70];
    __shared__ ushort vS[64 * 70];
    const int t = threadIdx.x, w = t >> 6, lane = t & 63;
    const int fr = lane & 15, fk = (lane >> 4) * 8;

    floatx4 acc[5] = {};
    const int n_ld = t >> 2, c16 = (t & 3) * 16;
    const ushort* base = QKV + (size_t)(bb * 4096 + s * 512) * 2304 + 768 + head * 64 + c16;

    for (int rr = 0; rr < 8; ++rr) {
        if (rr) __syncthreads();
        {
            const ushort* kp = base + (size_t)(rr * 64 + n_ld) * 2304;
            union { shortx8 v8; shortx2 v2[4]; } k0, k1, v0, v1;
            k0.v8 = *(const shortx8*)(kp);
            k1.v8 = *(const shortx8*)(kp + 8);
            v0.v8 = *(const shortx8*)(kp + 768);
            v1.v8 = *(const shortx8*)(kp + 776);
            ushort* kd = kS + n_ld * 70 + c16;
            ushort* vd = vS + n_ld * 70 + c16;
#pragma unroll
            for (int i = 0; i < 4; ++i) {
                *(shortx2*)(kd + 2 * i)     = k0.v2[i];
                *(shortx2*)(kd + 8 + 2 * i) = k1.v2[i];
                *(shortx2*)(vd + 2 * i)     = v0.v2[i];
                *(shortx2*)(vd + 8 + 2 * i) = v1.v2[i];
            }
        }
        __syncthreads();
#pragma unroll
        for (int kl = 0; kl < 64; kl += 32) {
            union { bf16x8 v; ushort u[8]; } bfr, afr[4];
#pragma unroll
            for (int i = 0; i < 8; ++i) {
                int n = kl + fk + i;
                bfr.u[i] = kS[n * 70 + w * 16 + fr];
#pragma unroll
                for (int mt = 0; mt < 4; ++mt)
                    afr[mt].u[i] = vS[n * 70 + mt * 16 + fr];
            }
            union { bf16x8 v; ushort u[8]; } ones;
            ushort ov = (fr == 0) ? (ushort)0x3F80 : (ushort)0;
#pragma unroll
            for (int i = 0; i < 8; ++i) ones.u[i] = ov;
#pragma unroll
            for (int mt = 0; mt < 4; ++mt)
                acc[mt] = mfma_bf16(afr[mt].v, bfr.v, acc[mt]);
            acc[4] = mfma_bf16(ones.v, bfr.v, acc[4]);
        }
    }

    float* dst = kvp + ((size_t)bh * 8 + s) * (65 * 64);
#pragma unroll
    for (int mt = 0; mt < 4; ++mt)
#pragma unroll
        for (int r = 0; r < 4; ++r)
            dst[(mt * 16 + (lane >> 4) * 4 + r) * 64 + w * 16 + fr] = acc[mt][r];
    if (lane < 16) dst[64 * 64 + w * 16 + lane] = acc[4][0];
}

// reduce 8 partials, emit bf16: kvb [48][65][64]
__global__ void k_kvred(const float* __restrict__ kvp, ushort* __restrict__ kvb) {
    int t4 = (blockIdx.x * 256 + threadIdx.x) * 4;   // 195*256*4 == 199680
    int bh = t4 / 4160, rem = t4 % 4160;
    const float* p = kvp + (size_t)bh * 8 * 4160 + rem;
    float4 sum = {0.f, 0.f, 0.f, 0.f};
    for (int i = 0; i < 8; ++i) {
        float4 a = *(const float4*)(p + (size_t)i * 4160);
        sum.x += a.x; sum.y += a.y; sum.z += a.z; sum.w += a.w;
    }
    shortx4 o;
    o[0] = (short)f2b(sum.x); o[1] = (short)f2b(sum.y);
    o[2] = (short)f2b(sum.z); o[3] = (short)f2b(sum.w);
    *(shortx4*)(kvb + t4) = o;
}

// ---------------- num + z + normed (MFMA, vector-store epilogue) -------------
__global__ __launch_bounds__(256) void k_num(const ushort* __restrict__ QKV,
                                             const ushort* __restrict__ kvb,
                                             ushort* __restrict__ normed) {
    const int bh = blockIdx.x, l0 = blockIdx.y * 128;
    const int bb = bh / 12, head = bh % 12;
    __shared__ ushort qsh[128 * 72];
    __shared__ ushort kvT[80 * 72];
    __shared__ float dnm[128];
    const int t = threadIdx.x, w = t >> 6, lane = t & 63;

    {
        const ushort* kvbb = kvb + (size_t)bh * 4160;
        int c8 = (t & 7) * 8;
        for (int r0 = (t >> 3); r0 < 65; r0 += 32)
            *(shortx8*)(kvT + r0 * 72 + c8) = *(const shortx8*)(kvbb + r0 * 64 + c8);
    }
    for (int idx = t; idx < 15 * 72; idx += 256) kvT[65 * 72 + idx] = 0;

    const ushort* qg = QKV + (size_t)(bb * 4096 + l0) * 2304 + head * 64;
    {
        int row = t >> 3, c8 = (t & 7) * 8;
#pragma unroll
        for (int i = 0; i < 4; ++i) {
            shortx8 v = *(const shortx8*)(qg + (size_t)(i * 32 + row) * 2304 + c8);
            *(shortx8*)(qsh + (i * 32 + row) * 72 + c8) = v;
        }
    }
    __syncthreads();

    const int fr = lane & 15, fk = (lane >> 4) * 8;
    floatx4 acc[2][5] = {};
#pragma unroll
    for (int kc = 0; kc < 2; ++kc) {
        bf16x8 a[2], b[5];
#pragma unroll
        for (int rt = 0; rt < 2; ++rt)
            a[rt] = *(const bf16x8*)(qsh + (w * 32 + rt * 16 + fr) * 72 + kc * 32 + fk);
#pragma unroll
        for (int nt = 0; nt < 5; ++nt)
            b[nt] = *(const bf16x8*)(kvT + (nt * 16 + fr) * 72 + kc * 32 + fk);
#pragma unroll
        for (int rt = 0; rt < 2; ++rt)
#pragma unroll
            for (int nt = 0; nt < 5; ++nt)
                acc[rt][nt] = mfma_bf16(a[rt], b[nt], acc[rt][nt]);
    }
    if (fr == 0) {
#pragma unroll
        for (int rt = 0; rt < 2; ++rt)
#pragma unroll
            for (int r = 0; r < 4; ++r)
                dnm[w * 32 + rt * 16 + (lane >> 4) * 4 + r] = acc[rt][4][r];
    }
    __syncthreads();

    ushort* osh = qsh;   // reuse
#pragma unroll
    for (int rt = 0; rt < 2; ++rt) {
#pragma unroll
        for (int r = 0; r < 4; ++r) {
            int ml = w * 32 + rt * 16 + (lane >> 4) * 4 + r;
            float z = 1.f / dnm[ml];
#pragma unroll
            for (int nt = 0; nt < 4; ++nt)
                osh[ml * 72 + nt * 16 + fr] = f2b(acc[rt][nt][r] * z);
        }
    }
    __syncthreads();
    {
        int row = t >> 3, c8 = (t & 7) * 8;
#pragma unroll
        for (int i = 0; i < 4; ++i) {
            int r2 = i * 32 + row;
            *(shortx8*)(normed + (size_t)(bb * 4096 + l0 + r2) * 768 + head * 64 + c8) =
                *(const shortx8*)(osh + r2 * 72 + c8);
        }
    }
}

// ---------------- launch ----------------
extern "C" void kernel_launch(void* const* d_in, const int* in_sizes, int n_in,
                              void* d_out, int out_size, void* d_ws, size_t ws_size,
                              hipStream_t stream) {
    const float* x  = (const float*)d_in[0];
    const float* Wq = (const float*)d_in[1];
    const float* bq = (const float*)d_in[2];
    const float* Wk = (const float*)d_in[3];
    const float* bk = (const float*)d_in[4];
    const float* Wv = (const float*)d_in[5];
    const float* bv = (const float*)d_in[6];
    const float* Wo = (const float*)d_in[7];
    const float* bo = (const float*)d_in[8];

    char* ws = (char*)d_ws;
    ushort* Xb   = (ushort*)(ws);                 // 25,165,824 B (reused as normed)
    ushort* Wt   = (ushort*)(ws + 25165824);      //  3,538,944 B
    ushort* Wot  = (ushort*)(ws + 28704768);      //  1,179,648 B
    float*  bqkv = (float*)(ws + 29884416);       //      9,216 B
    ushort* QKV  = (ushort*)(ws + 29893632);      // 75,497,472 B
    float*  kvp  = (float*)(ws + 105391104);      //  6,389,760 B
    ushort* kvb  = (ushort*)(ws + 111780864);     //    399,360 B
    ushort* normed = Xb;

    k_prep <<<dim3(6729),     256, 0, stream>>>(x, Xb, Wq, Wk, Wv, Wo, Wt, Wot,
                                                bq, bk, bv, bqkv);
    k_gemm<0><<<dim3(64, 18), 256, 0, stream>>>(Xb, Wt, bqkv, (void*)QKV, 2304);
    k_kv   <<<dim3(48, 8),    256, 0, stream>>>(QKV, kvp);
    k_kvred<<<dim3(195),      256, 0, stream>>>(kvp, kvb);
    k_num  <<<dim3(48, 32),   256, 0, stream>>>(QKV, kvb, normed);
    k_gemm<1><<<dim3(64, 6),  256, 0, stream>>>(normed, Wot, bo, d_out, 768);
}